// Round 11
// baseline (118.625 us; speedup 1.0000x reference)
//
#include <hip/hip_runtime.h>
#include <math.h>

// MatchNet: MLP(6->20->20->20->8, tanh) then 150-iter PDHG LP per row.
// R11 = DISCRIMINATING PROBE, not an optimization: the R9/R10 verified
// 2-lane choreography run with each row DUPLICATED across the two lane
// pairs of a quad (pairs (0,1) and (2,3) compute the same row; only pair 0
// stores). Waves 1024 -> 2048 = 2 waves/SIMD. This tests whether the
// measured 2.78ns/slot issue cadence is per-WAVE (two waves interleave
// freely -> harness time unchanged -> R12 builds a real 4-lane split) or
// per-SIMD (waves contend -> harness ~+30us -> R10 is the structural
// floor). All numerics byte-identical to R10: absmax must stay exactly
// 0.001953125. DPP quad_perm[1,0,3,2] is pair-local, so both pairs run
// the exchange correctly and independently.

#define N_ITERS 150
typedef float f2 __attribute__((ext_vector_type(2)));
typedef float f4 __attribute__((ext_vector_type(4)));

__device__ __forceinline__ float fast_tanh(float a) {
    float e = __expf(2.0f * a);
    return 1.0f - 2.0f * __builtin_amdgcn_rcpf(e + 1.0f);
}

__device__ __forceinline__ float dpp_swap(float v) {
    // quad_perm [1,0,3,2]: lane pairs (2k,2k+1) exchange
    union { float f; int i; } u;
    u.f = v;
    u.i = __builtin_amdgcn_update_dpp(0, u.i, 0xB1, 0xF, 0xF, true);
    return u.f;
}

__global__ void __launch_bounds__(64)
__attribute__((amdgpu_waves_per_eu(2)))
matchnet_kernel(
    const float* __restrict__ X,
    const float* __restrict__ W1, const float* __restrict__ b1,
    const float* __restrict__ W2, const float* __restrict__ b2,
    const float* __restrict__ W3, const float* __restrict__ b3,
    const float* __restrict__ W4, const float* __restrict__ b4,
    float* __restrict__ out, int B)
{
    // Transposed weights: tW1[j*8+i] (i<6, pad 8), tW2/tW3[j*20+i], tW4[k*20+i]
    __shared__ alignas(16) float tW1[160], tW2[400], tW3[400], tW4[160];
    __shared__ alignas(16) float sb1[20], sb2[20], sb3[20], sb4[8];
    {
        int tid = threadIdx.x;
        for (int idx = tid; idx < 120; idx += 64) { int i = idx / 20, j = idx % 20; tW1[j * 8 + i] = W1[idx]; }
        for (int idx = tid; idx < 400; idx += 64) { int i = idx / 20, j = idx % 20; tW2[j * 20 + i] = W2[idx]; }
        for (int idx = tid; idx < 400; idx += 64) { int i = idx / 20, j = idx % 20; tW3[j * 20 + i] = W3[idx]; }
        for (int idx = tid; idx < 160; idx += 64) { int i = idx / 8,  k = idx % 8;  tW4[k * 20 + i] = W4[idx]; }
        if (tid < 20) { sb1[tid] = b1[tid]; sb2[tid] = b2[tid]; sb3[tid] = b3[tid]; }
        if (tid < 8) sb4[tid] = b4[tid];
    }
    __syncthreads();

    int gidx = blockIdx.x * blockDim.x + threadIdx.x;
    int row  = gidx >> 2;           // 4 lanes per row (2 duplicate pairs)
    if (row >= B) return;
    int sub = gidx & 3;             // 0,1 = pair A; 2,3 = pair B (duplicate)
    const bool isOdd = (sub & 1) != 0;
    const bool isPairA = (sub < 2);
    const int jb = isOdd ? 10 : 0;   // this lane's neuron range (layers 1-3)
    const int kb = isOdd ? 4 : 0;    // this lane's output range (layer 4)

    float bb0 = X[row * 6 + 0], bb1 = X[row * 6 + 1], bb2 = X[row * 6 + 2];
    float bb3 = X[row * 6 + 3], bb4 = X[row * 6 + 4], bb5 = X[row * 6 + 5];

    // --- MLP, neuron-split across each lane pair (pairs duplicate) ---
    float hA[10], hB[10];   // absolute h[0..9], h[10..19] (both lanes)
    {
        float acc[10];
        const f2* bv = (const f2*)&sb1[jb];
        #pragma unroll
        for (int p = 0; p < 5; p++) { f2 b = bv[p]; acc[2 * p] = b.x; acc[2 * p + 1] = b.y; }
        #pragma unroll
        for (int n = 0; n < 10; n++) {
            int j = jb + n;
            f4 w0 = *(const f4*)&tW1[j * 8];
            f2 w1 = *(const f2*)&tW1[j * 8 + 4];
            float a = acc[n];
            a = fmaf(bb0, w0.x, a); a = fmaf(bb1, w0.y, a); a = fmaf(bb2, w0.z, a);
            a = fmaf(bb3, w0.w, a); a = fmaf(bb4, w1.x, a); a = fmaf(bb5, w1.y, a);
            acc[n] = fast_tanh(a);
        }
        #pragma unroll
        for (int n = 0; n < 10; n++) {
            float t = dpp_swap(acc[n]);
            hA[n] = isOdd ? t : acc[n];
            hB[n] = isOdd ? acc[n] : t;
        }
    }
    #pragma unroll
    for (int layer = 0; layer < 2; layer++) {
        const float* tw = layer ? tW3 : tW2;
        const float* sb = layer ? sb3 : sb2;
        float acc[10];
        const f2* bv = (const f2*)&sb[jb];
        #pragma unroll
        for (int p = 0; p < 5; p++) { f2 b = bv[p]; acc[2 * p] = b.x; acc[2 * p + 1] = b.y; }
        #pragma unroll
        for (int n = 0; n < 10; n++) {
            int j = jb + n;
            const f4* w = (const f4*)&tw[j * 20];
            f4 w0 = w[0], w1 = w[1], w2 = w[2], w3 = w[3], w4 = w[4];
            float a = acc[n];
            a = fmaf(hA[0], w0.x, a); a = fmaf(hA[1], w0.y, a);
            a = fmaf(hA[2], w0.z, a); a = fmaf(hA[3], w0.w, a);
            a = fmaf(hA[4], w1.x, a); a = fmaf(hA[5], w1.y, a);
            a = fmaf(hA[6], w1.z, a); a = fmaf(hA[7], w1.w, a);
            a = fmaf(hA[8], w2.x, a); a = fmaf(hA[9], w2.y, a);
            a = fmaf(hB[0], w2.z, a); a = fmaf(hB[1], w2.w, a);
            a = fmaf(hB[2], w3.x, a); a = fmaf(hB[3], w3.y, a);
            a = fmaf(hB[4], w3.z, a); a = fmaf(hB[5], w3.w, a);
            a = fmaf(hB[6], w4.x, a); a = fmaf(hB[7], w4.y, a);
            a = fmaf(hB[8], w4.z, a); a = fmaf(hB[9], w4.w, a);
            acc[n] = fast_tanh(a);
        }
        #pragma unroll
        for (int n = 0; n < 10; n++) {
            float t = dpp_swap(acc[n]);
            hA[n] = isOdd ? t : acc[n];
            hB[n] = isOdd ? acc[n] : t;
        }
    }
    // L4: this lane's 4 outputs == exactly its z components (no exchange)
    float oz0, oz1, oz2, oz3;
    {
        f4 b = *(const f4*)&sb4[kb];
        float acc[4] = {b.x, b.y, b.z, b.w};
        #pragma unroll
        for (int n = 0; n < 4; n++) {
            int k = kb + n;
            const f4* w = (const f4*)&tW4[k * 20];
            f4 w0 = w[0], w1 = w[1], w2 = w[2], w3 = w[3], w4 = w[4];
            float a = acc[n];
            a = fmaf(hA[0], w0.x, a); a = fmaf(hA[1], w0.y, a);
            a = fmaf(hA[2], w0.z, a); a = fmaf(hA[3], w0.w, a);
            a = fmaf(hA[4], w1.x, a); a = fmaf(hA[5], w1.y, a);
            a = fmaf(hA[6], w1.z, a); a = fmaf(hA[7], w1.w, a);
            a = fmaf(hA[8], w2.x, a); a = fmaf(hA[9], w2.y, a);
            a = fmaf(hB[0], w2.z, a); a = fmaf(hB[1], w2.w, a);
            a = fmaf(hB[2], w3.x, a); a = fmaf(hB[3], w3.y, a);
            a = fmaf(hB[4], w3.z, a); a = fmaf(hB[5], w3.w, a);
            a = fmaf(hB[6], w4.x, a); a = fmaf(hB[7], w4.y, a);
            a = fmaf(hB[8], w4.z, a); a = fmaf(hB[9], w4.w, a);
            acc[n] = a;
        }
        oz0 = acc[0]; oz1 = acc[1]; oz2 = acc[2]; oz3 = acc[3];
    }

    // --- constants ---
    const float tau  = 0.18898223650461363f;   // 1/sqrt(28)
    const float c    = 0.03571428571428571f;   // tau*sigma = 1/28
    const float tauC = 1.8898223650461363f;    // tau * control_strength(10)

    float ot0 = tau - oz0, ot1 = tau - oz1, ot2 = tau - oz2, ot3 = tau - oz3;
    float oTI0 = ot0, oTI1 = ot1, oTI2 = ot2, oTI3 = ot3;

    float ox0 = fmaxf(oz0, 0.f), ox1 = fmaxf(oz1, 0.f);
    float ox2 = fmaxf(oz2, 0.f), ox3 = fmaxf(oz3, 0.f);
    float oxb0 = ox0, oxb1 = ox1, oxb2 = ox2, oxb3 = ox3;

    // dual-row constants: even rows (0,2,1) -> (cb0,cb2,cb1); odd (4,3,5)
    float cb0 = c * bb0, cb1 = c * bb1, cb2 = c * bb2;
    float cb3 = c * bb3, cb4 = c * bb4, cb5 = c * bb5;
    float cbq0 = isOdd ? cb4 : cb0;
    float cbq1 = isOdd ? cb3 : cb2;
    float cbq2 = isOdd ? cb5 : cb1;
    float Yq0 = 0.f, Yq1 = 0.f, Yq2 = 0.f;

    #pragma unroll 1
    for (int it = 0; it < N_ITERS; it++) {
        // xb exchange (4)
        float rxb0 = dpp_swap(oxb0), rxb1 = dpp_swap(oxb1);
        float rxb2 = dpp_swap(oxb2), rxb3 = dpp_swap(oxb3);

        // s-sums (12): even (s0,s2,s1), odd (s4,s3,s5)
        float op_a = oxb0 + rxb1;            // e: xb0+xb5 | o: xb4+xb1
        float op_b = oxb2 + rxb3;            // e: xb2+xb7 | o: garbage
        float op_c = oxb3 + rxb2;            // e: garbage | o: xb7+xb2
        float op_d = isOdd ? op_c : op_b;
        float sq0  = op_a + op_d;            // e: s0 | o: s4
        float op_e = oxb1 + rxb2;            // e: xb1+xb6 | o: xb5+xb2
        float op_f = isOdd ? rxb3 : oxb0;    // e: xb0 | o: xb3
        float sq1  = op_e + op_f;            // e: s2 | o: s3
        float op_g = oxb1 + oxb3;            // e: xb1+xb3
        float op_h = oxb0 + oxb2;            //            o: xb4+xb6
        float op_i = isOdd ? op_h : op_g;
        float sq2  = op_i + rxb0;            // e: s1 | o: s5

        // Y updates (9)
        Yq0 = fmaxf(0.f, fmaf(c, sq0, Yq0) - cbq0);
        Yq1 = fmaxf(0.f, fmaf(c, sq1, Yq1) - cbq1);
        Yq2 = fmaxf(0.f, fmaf(c, sq2, Yq2) - cbq2);

        // Y exchange (3)
        float rY0 = dpp_swap(Yq0), rY1 = dpp_swap(Yq1), rY2 = dpp_swap(Yq2);

        // column sums (11): even cols 0-3, odd cols 4-7
        float op_j = Yq0 + rY2;              // e: Y0+Y5 | o: Y4+Y1
        float op_k = isOdd ? Yq2 : Yq1;      // e: Y2    | o: Y5
        float colq0 = op_j + op_k;           // e: col0  | o: col4
        float op_l = Yq1 + rY0;              // e: Y2+Y4 | o: Y3+Y0
        float op_p = isOdd ? 0.f : Yq2;      // e: Y1    | o: 0
        float colq1 = op_l + op_p;           // e: col1  | o: col5
        float op_m = Yq0 + rY0;              // e: Y0+Y4 | o: Y4+Y0 (=col7)
        float op_n = rY1 + Yq2;              // e: Y3+Y1 (=col3) | o: Y2+Y5 (=col6)
        float op_o = op_m + rY1;             // e: Y0+Y4+Y3 (=col2) | o: garbage
        float colq2 = isOdd ? op_n : op_o;   // e: col2 | o: col6
        float colq3 = isOdd ? op_m : op_n;   // e: col3 | o: col7

        // TI (8)
        oTI0 = fmaxf(ot0, fmaf(-c, oxb0, oTI0));
        oTI1 = fmaxf(ot1, fmaf(-c, oxb1, oTI1));
        oTI2 = fmaxf(ot2, fmaf(-c, oxb2, oTI2));
        oTI3 = fmaxf(ot3, fmaf(-c, oxb3, oTI3));

        // d = (x + TI) - col  (8)
        float od0 = (ox0 + oTI0) - colq0;
        float od1 = (ox1 + oTI1) - colq1;
        float od2 = (ox2 + oTI2) - colq2;
        float od3 = (ox3 + oTI3) - colq3;

        // nsq (6)
        float nl = od0 * od0;
        nl = fmaf(od1, od1, nl);
        nl = fmaf(od2, od2, nl);
        nl = fmaf(od3, od3, nl);
        float rn = dpp_swap(nl);
        float nsq = nl + rn;

        // scale (3)
        float rs = __builtin_amdgcn_rsqf(nsq);
        float scale = fmaxf(0.f, fmaf(-tauC, rs, 1.f));

        // xn + xb commit (8)
        float xn0 = fmaf(scale, od0, oz0);
        float xn1 = fmaf(scale, od1, oz1);
        float xn2 = fmaf(scale, od2, oz2);
        float xn3 = fmaf(scale, od3, oz3);
        oxb0 = fmaf(2.f, xn0, -ox0); ox0 = xn0;
        oxb1 = fmaf(2.f, xn1, -ox1); ox1 = xn1;
        oxb2 = fmaf(2.f, xn2, -ox2); ox2 = xn2;
        oxb3 = fmaf(2.f, xn3, -ox3); ox3 = xn3;
    }

    // only pair A stores (pair B is the duplicate)
    if (isPairA) {
        float4* out4 = (float4*)out;
        out4[row * 2 + (isOdd ? 1 : 0)] = make_float4(ox0, ox1, ox2, ox3);
    }
}

extern "C" void kernel_launch(void* const* d_in, const int* in_sizes, int n_in,
                              void* d_out, int out_size, void* d_ws, size_t ws_size,
                              hipStream_t stream) {
    const float* X  = (const float*)d_in[0];
    const float* W1 = (const float*)d_in[1];
    const float* b1 = (const float*)d_in[2];
    const float* W2 = (const float*)d_in[3];
    const float* b2 = (const float*)d_in[4];
    const float* W3 = (const float*)d_in[5];
    const float* b3 = (const float*)d_in[6];
    const float* W4 = (const float*)d_in[7];
    const float* b4 = (const float*)d_in[8];
    float* out = (float*)d_out;

    int B = in_sizes[0] / 6;
    const int block = 64;
    long long threads = (long long)B * 4;   // 2 duplicate pairs per row
    int grid = (int)((threads + block - 1) / block);
    hipLaunchKernelGGL(matchnet_kernel, dim3(grid), dim3(block), 0, stream,
                       X, W1, b1, W2, b2, W3, b3, W4, b4, out, B);
}

// Round 12
// 111.920 us; speedup vs baseline: 1.0599x; 1.0599x over previous
//
#include <hip/hip_runtime.h>
#include <math.h>

// MatchNet: MLP(6->20->20->20->8, tanh) then 150-iter PDHG LP per row.
// R12: FOUR LANES PER ROW. Components L0:{0,1} L1:{2,3} L2:{4,5} L3:{6,7}
// (a=even comp, b=odd comp per lane). S-rows: Y1 = r0@L0,r1@L1,r4@L2,r5@L3;
// Y2 = r2@L0,r3@L1 (L2/L3 Y2 is bounded garbage, never used).
// All cross-lane traffic via quad_perm DPP; lane-dependent operand choice
// via loop-invariant ternaries (v_cmp hoisted, 1 v_cndmask each in-loop).
// Loop = ~61 issue slots vs R10's 72. Cadence model (R1-R11): wall =
// slots/wave x 2.78ns, per-WAVE cadence (R11: VALUBusy 63% at 2 waves/SIMD
// = 2x29%, free interleave). waves_per_eu(2,2): 256-VGPR budget, 2 resident
// waves/SIMD, no spill-mode (R11's VGPR-36 failure).
// MLP: R9/R10/R11-verified pair scheme (bit-exact), + z redistribution.
// absmax oracle: must be exactly 0.001953125.

#define N_ITERS 150
typedef float f2 __attribute__((ext_vector_type(2)));
typedef float f4 __attribute__((ext_vector_type(4)));

__device__ __forceinline__ float fast_tanh(float a) {
    float e = __expf(2.0f * a);
    return 1.0f - 2.0f * __builtin_amdgcn_rcpf(e + 1.0f);
}

template <int CTRL>
__device__ __forceinline__ float qperm(float v) {
    union { float f; int i; } u;
    u.f = v;
    u.i = __builtin_amdgcn_update_dpp(0, u.i, CTRL, 0xF, 0xF, true);
    return u.f;
}
// quad_perm ctrl = a | b<<2 | c<<4 | d<<6 (lane i reads lane perm[i])
#define QP(a,b,c,d) ((a) | ((b)<<2) | ((c)<<4) | ((d)<<6))

__global__ void __launch_bounds__(64)
__attribute__((amdgpu_waves_per_eu(2, 2)))
matchnet_kernel(
    const float* __restrict__ X,
    const float* __restrict__ W1, const float* __restrict__ b1,
    const float* __restrict__ W2, const float* __restrict__ b2,
    const float* __restrict__ W3, const float* __restrict__ b3,
    const float* __restrict__ W4, const float* __restrict__ b4,
    float* __restrict__ out, int B)
{
    // Transposed weights: tW1[j*8+i] (i<6, pad 8), tW2/tW3[j*20+i], tW4[k*20+i]
    __shared__ alignas(16) float tW1[160], tW2[400], tW3[400], tW4[160];
    __shared__ alignas(16) float sb1[20], sb2[20], sb3[20], sb4[8];
    {
        int tid = threadIdx.x;
        for (int idx = tid; idx < 120; idx += 64) { int i = idx / 20, j = idx % 20; tW1[j * 8 + i] = W1[idx]; }
        for (int idx = tid; idx < 400; idx += 64) { int i = idx / 20, j = idx % 20; tW2[j * 20 + i] = W2[idx]; }
        for (int idx = tid; idx < 400; idx += 64) { int i = idx / 20, j = idx % 20; tW3[j * 20 + i] = W3[idx]; }
        for (int idx = tid; idx < 160; idx += 64) { int i = idx / 8,  k = idx % 8;  tW4[k * 20 + i] = W4[idx]; }
        if (tid < 20) { sb1[tid] = b1[tid]; sb2[tid] = b2[tid]; sb3[tid] = b3[tid]; }
        if (tid < 8) sb4[tid] = b4[tid];
    }
    __syncthreads();

    int gidx = blockIdx.x * blockDim.x + threadIdx.x;
    int row  = gidx >> 2;            // 4 lanes per row
    if (row >= B) return;
    const int  sub     = gidx & 3;   // quad lane L0..L3
    const bool pairOdd = (sub & 1) != 0;   // pair parity (MLP scheme)
    const bool isL1  = (sub == 1);
    const bool isL2  = (sub == 2);
    const bool isL3  = (sub == 3);
    const bool isL12 = (sub == 1) || (sub == 2);
    const bool isL23 = (sub >= 2);
    const bool isL13 = isL1 || isL3;
    const bool notL0 = (sub != 0);
    const int jb = pairOdd ? 10 : 0;
    const int kb = pairOdd ? 4 : 0;

    float bb0 = X[row * 6 + 0], bb1 = X[row * 6 + 1], bb2 = X[row * 6 + 2];
    float bb3 = X[row * 6 + 3], bb4 = X[row * 6 + 4], bb5 = X[row * 6 + 5];

    // --- MLP, pair scheme (verified bit-exact R9/R10/R11); pairs duplicate ---
    float hA[10], hB[10];
    {
        float acc[10];
        const f2* bv = (const f2*)&sb1[jb];
        #pragma unroll
        for (int p = 0; p < 5; p++) { f2 b = bv[p]; acc[2 * p] = b.x; acc[2 * p + 1] = b.y; }
        #pragma unroll
        for (int n = 0; n < 10; n++) {
            int j = jb + n;
            f4 w0 = *(const f4*)&tW1[j * 8];
            f2 w1 = *(const f2*)&tW1[j * 8 + 4];
            float a = acc[n];
            a = fmaf(bb0, w0.x, a); a = fmaf(bb1, w0.y, a); a = fmaf(bb2, w0.z, a);
            a = fmaf(bb3, w0.w, a); a = fmaf(bb4, w1.x, a); a = fmaf(bb5, w1.y, a);
            acc[n] = fast_tanh(a);
        }
        #pragma unroll
        for (int n = 0; n < 10; n++) {
            float t = qperm<QP(1,0,3,2)>(acc[n]);
            hA[n] = pairOdd ? t : acc[n];
            hB[n] = pairOdd ? acc[n] : t;
        }
    }
    #pragma unroll
    for (int layer = 0; layer < 2; layer++) {
        const float* tw = layer ? tW3 : tW2;
        const float* sb = layer ? sb3 : sb2;
        float acc[10];
        const f2* bv = (const f2*)&sb[jb];
        #pragma unroll
        for (int p = 0; p < 5; p++) { f2 b = bv[p]; acc[2 * p] = b.x; acc[2 * p + 1] = b.y; }
        #pragma unroll
        for (int n = 0; n < 10; n++) {
            int j = jb + n;
            const f4* w = (const f4*)&tw[j * 20];
            f4 w0 = w[0], w1 = w[1], w2 = w[2], w3 = w[3], w4 = w[4];
            float a = acc[n];
            a = fmaf(hA[0], w0.x, a); a = fmaf(hA[1], w0.y, a);
            a = fmaf(hA[2], w0.z, a); a = fmaf(hA[3], w0.w, a);
            a = fmaf(hA[4], w1.x, a); a = fmaf(hA[5], w1.y, a);
            a = fmaf(hA[6], w1.z, a); a = fmaf(hA[7], w1.w, a);
            a = fmaf(hA[8], w2.x, a); a = fmaf(hA[9], w2.y, a);
            a = fmaf(hB[0], w2.z, a); a = fmaf(hB[1], w2.w, a);
            a = fmaf(hB[2], w3.x, a); a = fmaf(hB[3], w3.y, a);
            a = fmaf(hB[4], w3.z, a); a = fmaf(hB[5], w3.w, a);
            a = fmaf(hB[6], w4.x, a); a = fmaf(hB[7], w4.y, a);
            a = fmaf(hB[8], w4.z, a); a = fmaf(hB[9], w4.w, a);
            acc[n] = fast_tanh(a);
        }
        #pragma unroll
        for (int n = 0; n < 10; n++) {
            float t = qperm<QP(1,0,3,2)>(acc[n]);
            hA[n] = pairOdd ? t : acc[n];
            hB[n] = pairOdd ? acc[n] : t;
        }
    }
    // L4: 4 outputs per pair-lane (even: z0..3, odd: z4..7)
    float oz0, oz1, oz2, oz3;
    {
        f4 b = *(const f4*)&sb4[kb];
        float acc[4] = {b.x, b.y, b.z, b.w};
        #pragma unroll
        for (int n = 0; n < 4; n++) {
            int k = kb + n;
            const f4* w = (const f4*)&tW4[k * 20];
            f4 w0 = w[0], w1 = w[1], w2 = w[2], w3 = w[3], w4 = w[4];
            float a = acc[n];
            a = fmaf(hA[0], w0.x, a); a = fmaf(hA[1], w0.y, a);
            a = fmaf(hA[2], w0.z, a); a = fmaf(hA[3], w0.w, a);
            a = fmaf(hA[4], w1.x, a); a = fmaf(hA[5], w1.y, a);
            a = fmaf(hA[6], w1.z, a); a = fmaf(hA[7], w1.w, a);
            a = fmaf(hA[8], w2.x, a); a = fmaf(hA[9], w2.y, a);
            a = fmaf(hB[0], w2.z, a); a = fmaf(hB[1], w2.w, a);
            a = fmaf(hB[2], w3.x, a); a = fmaf(hB[3], w3.y, a);
            a = fmaf(hB[4], w3.z, a); a = fmaf(hB[5], w3.w, a);
            a = fmaf(hB[6], w4.x, a); a = fmaf(hB[7], w4.y, a);
            a = fmaf(hB[8], w4.z, a); a = fmaf(hB[9], w4.w, a);
            acc[n] = a;
        }
        oz0 = acc[0]; oz1 = acc[1]; oz2 = acc[2]; oz3 = acc[3];
    }

    // --- z redistribution: pair layout -> quad layout (za,zb per lane) ---
    // even pair-lanes hold z0..3 in oz0..3; odd hold z4..7.
    // Targets: L0:(z0,z1) L1:(z2,z3) L2:(z4,z5) L3:(z6,z7).
    float za, zb;
    {
        float dZ1 = qperm<QP(0,0,3,3)>(oz2);   // L1 <- L0.oz2 = z2
        float dZ2 = qperm<QP(3,3,3,3)>(oz0);   // L2 <- L3.oz0 = z4
        float t   = isL3 ? oz2 : oz0;          // L0:z0, L3:z6
        t  = isL1 ? dZ1 : t;                   // L1:z2
        za = isL2 ? dZ2 : t;                   // L2:z4
        float dZ3 = qperm<QP(0,0,0,0)>(oz3);   // L1 <- L0.oz3 = z3
        float dZ4 = qperm<QP(3,3,3,3)>(oz1);   // L2 <- L3.oz1 = z5
        float u   = isL3 ? oz3 : oz1;          // L0:z1, L3:z7
        u  = isL1 ? dZ3 : u;                   // L1:z3
        zb = isL2 ? dZ4 : u;                   // L2:z5
    }

    // --- PDHG constants / per-lane dual constants ---
    const float tau  = 0.18898223650461363f;   // 1/sqrt(28)
    const float c    = 0.03571428571428571f;   // tau*sigma = 1/28
    const float tauC = 1.8898223650461363f;    // tau * control_strength(10)

    float cb0 = c * bb0, cb1 = c * bb1, cb2 = c * bb2;
    float cb3 = c * bb3, cb4 = c * bb4, cb5 = c * bb5;
    float cb1q = isL1 ? cb1 : cb0;  cb1q = isL2 ? cb4 : cb1q;  cb1q = isL3 ? cb5 : cb1q;
    float cb2q = isL1 ? cb3 : cb2;  // L2/L3: cb2 (bounded garbage path)

    float ta = tau - za, tb = tau - zb;
    float TIa = ta, TIb = tb;
    float xa = fmaxf(za, 0.f), xb_ = fmaxf(zb, 0.f);
    float xba = xa, xbb = xb_;      // xbar
    float Y1 = 0.f, Y2 = 0.f;

    #pragma unroll 1
    for (int it = 0; it < N_ITERS; it++) {
        // ---- stage 1: xbar exchange + row sums (15) ----
        // xbar_a: L0:x0 L1:x2 L2:x4 L3:x6 ; xbar_b: L0:x1 L1:x3 L2:x5 L3:x7
        float dA1 = qperm<QP(1,2,1,0)>(xba);   // L0:x2 L1:x4 L2:x2 L3:x0
        float dA2 = qperm<QP(2,2,2,2)>(xba);   // all: x4 (L3 uses)
        float dB1 = qperm<QP(2,0,0,0)>(xbb);   // L0:x5 L1:x1 L2:x1
        float dB2 = qperm<QP(3,3,3,3)>(xbb);   // all: x7 (L0,L2 use)
        float P = isL1 ? xbb : xba;            // L0:x0 L1:x3 L2:x4 L3:x6
        float R = isL3 ? dA2 : dB1;            // L0:x5 L1:x1 L2:x1 L3:x4
        float T = isL13 ? 0.f : dB2;           // L0:x7 L1:0  L2:x7 L3:0
        float s1 = (P + dA1) + (R + T);        // r0 | r1 | r4 | r5
        float dA3 = qperm<QP(3,3,3,3)>(xba);   // all: x6 (L0 uses)
        float dB3 = qperm<QP(2,2,2,2)>(xbb);   // all: x5 (L1 uses)
        float V = isL1 ? dB3 : dA3;
        float s2 = (xba + xbb) + V;            // r2 @L0 | r3 @L1 | (bounded junk)

        // ---- stage 2: Y updates (6) ----
        Y1 = fmaxf(0.f, fmaf(c, s1, Y1) - cb1q);
        Y2 = fmaxf(0.f, fmaf(c, s2, Y2) - cb2q);

        // ---- stage 3: column sums (19) ----
        // Y1: L0:r0 L1:r1 L2:r4 L3:r5 ; Y2: L0:r2 L1:r3
        float gYa = qperm<QP(3,0,1,0)>(Y1);    // L0:r5 L1:r0 L2:r1 L3:r0
        float gYb = qperm<QP(1,2,3,2)>(Y1);    // L0:r1 L1:r4 L2:r5 L3:r4
        float gYc = qperm<QP(2,2,0,0)>(Y1);    // L0:r4 L2:r0
        float gY2 = qperm<QP(1,0,1,0)>(Y2);    // L2:r3 L3:r2
        // colA: c0=r0+r2+r5 | c2=r0+r3+r4 | c4=r1+r4+r5 | c6=r2+r5
        float T1 = isL12 ? gYa : Y1;  T1 = isL3 ? gY2 : T1;   // r0|r0|r1|r2
        float T2 = isL23 ? Y1  : Y2;                          // r2|r3|r4|r5
        float T3 = isL12 ? gYb : gYa; T3 = isL3 ? 0.f : T3;   // r5|r4|r5|0
        float colA = (T1 + T2) + T3;
        // colB: c1=r1+r2+r4 | c3=r1+r3 | c5=r0+r3 | c7=r0+r4
        float U1 = isL1 ? Y1  : gYb;  U1 = isL2 ? gYc : U1;  U1 = isL3 ? gYa : U1; // r1|r1|r0|r0
        float U2 = isL2 ? gY2 : Y2;   U2 = isL3 ? gYb : U2;                        // r2|r3|r3|r4
        float U3 = notL0 ? 0.f : gYc;                                              // r4|0|0|0
        float colB = (U1 + U2) + U3;

        // ---- TI (4): TI = max(t, fma(-c, xbar, TI)) ----
        TIa = fmaxf(ta, fmaf(-c, xba, TIa));
        TIb = fmaxf(tb, fmaf(-c, xbb, TIb));

        // ---- d (4) ----
        float da = (xa  + TIa) - colA;
        float db = (xb_ + TIb) - colB;

        // ---- nsq quad-reduce (6), commutative adds -> bit-identical lanes ----
        float p  = fmaf(db, db, da * da);
        float pp = p + qperm<QP(1,0,3,2)>(p);
        float nsq = pp + qperm<QP(2,3,0,1)>(pp);

        // ---- scale (3): rsq(0)=inf -> scale=0 == ref clamp ----
        float rs = __builtin_amdgcn_rsqf(nsq);
        float scale = fmaxf(0.f, fmaf(-tauC, rs, 1.f));

        // ---- xn + xbar commit (4) ----
        float xna = fmaf(scale, da, za);
        float xnb = fmaf(scale, db, zb);
        xba = fmaf(2.f, xna, -xa);  xa  = xna;
        xbb = fmaf(2.f, xnb, -xb_); xb_ = xnb;
    }

    // lane stores its 2 components: floats [row*8 + 2*sub, +1]
    f2* out2 = (f2*)out;
    f2 vo; vo.x = xa; vo.y = xb_;
    out2[gidx] = vo;
}

extern "C" void kernel_launch(void* const* d_in, const int* in_sizes, int n_in,
                              void* d_out, int out_size, void* d_ws, size_t ws_size,
                              hipStream_t stream) {
    const float* X  = (const float*)d_in[0];
    const float* W1 = (const float*)d_in[1];
    const float* b1 = (const float*)d_in[2];
    const float* W2 = (const float*)d_in[3];
    const float* b2 = (const float*)d_in[4];
    const float* W3 = (const float*)d_in[5];
    const float* b3 = (const float*)d_in[6];
    const float* W4 = (const float*)d_in[7];
    const float* b4 = (const float*)d_in[8];
    float* out = (float*)d_out;

    int B = in_sizes[0] / 6;
    const int block = 64;
    long long threads = (long long)B * 4;   // 4 lanes per row
    int grid = (int)((threads + block - 1) / block);
    hipLaunchKernelGGL(matchnet_kernel, dim3(grid), dim3(block), 0, stream,
                       X, W1, b1, W2, b2, W3, b3, W4, b4, out, B);
}

// Round 13
// 103.046 us; speedup vs baseline: 1.1512x; 1.0861x over previous
//
#include <hip/hip_runtime.h>
#include <math.h>

// MatchNet: MLP(6->20->20->20->8, tanh) then 150-iter PDHG LP per row.
// R13 = REVERT to R10 (measured optimum, 101.7us harness / ~34us kernel).
//
// Final model (R1-R12): aggregate per-SIMD VALU issue saturates at
// ~0.42e9 inst/s regardless of wave count (R12: 2 waves/SIMD halve each
// wave's cadence; R11's "free interleave" read was wrong). Lane-split
// ledger (machine-wide inst): 1-lane 7.5M/44us, 2-lane 12.2M/34us,
// 4-lane 20.8M/48us -> 2-lane is the optimum (wave count x slots tradeoff).
// Loop choreography = 72 slots/iter, enumerated minimal per stage.
// N_ITERS pinned at 150 (R6: trajectory moves ~0.5 between it 100..150).
// absmax oracle: exactly 0.001953125 (bit-exact vs R4/R8 scalar algebra).
//
// TWO LANES PER ROW (even lane owns comps 0-3, odd owns 4-7), state
// lane-relative, DPP quad_perm[1,0,3,2] pair exchange. MLP neuron-split
// 10/10 across the pair, transposed LDS weights, bit-exact reassembly.

#define N_ITERS 150
typedef float f2 __attribute__((ext_vector_type(2)));
typedef float f4 __attribute__((ext_vector_type(4)));

__device__ __forceinline__ float fast_tanh(float a) {
    float e = __expf(2.0f * a);
    return 1.0f - 2.0f * __builtin_amdgcn_rcpf(e + 1.0f);
}

__device__ __forceinline__ float dpp_swap(float v) {
    // quad_perm [1,0,3,2]: lane pairs (2k,2k+1) exchange
    union { float f; int i; } u;
    u.f = v;
    u.i = __builtin_amdgcn_update_dpp(0, u.i, 0xB1, 0xF, 0xF, true);
    return u.f;
}

__global__ void __launch_bounds__(64)
__attribute__((amdgpu_waves_per_eu(1, 1)))
matchnet_kernel(
    const float* __restrict__ X,
    const float* __restrict__ W1, const float* __restrict__ b1,
    const float* __restrict__ W2, const float* __restrict__ b2,
    const float* __restrict__ W3, const float* __restrict__ b3,
    const float* __restrict__ W4, const float* __restrict__ b4,
    float* __restrict__ out, int B)
{
    // Transposed weights: tW1[j*8+i] (i<6, pad 8), tW2/tW3[j*20+i], tW4[k*20+i]
    __shared__ alignas(16) float tW1[160], tW2[400], tW3[400], tW4[160];
    __shared__ alignas(16) float sb1[20], sb2[20], sb3[20], sb4[8];
    {
        int tid = threadIdx.x;
        for (int idx = tid; idx < 120; idx += 64) { int i = idx / 20, j = idx % 20; tW1[j * 8 + i] = W1[idx]; }
        for (int idx = tid; idx < 400; idx += 64) { int i = idx / 20, j = idx % 20; tW2[j * 20 + i] = W2[idx]; }
        for (int idx = tid; idx < 400; idx += 64) { int i = idx / 20, j = idx % 20; tW3[j * 20 + i] = W3[idx]; }
        for (int idx = tid; idx < 160; idx += 64) { int i = idx / 8,  k = idx % 8;  tW4[k * 20 + i] = W4[idx]; }
        if (tid < 20) { sb1[tid] = b1[tid]; sb2[tid] = b2[tid]; sb3[tid] = b3[tid]; }
        if (tid < 8) sb4[tid] = b4[tid];
    }
    __syncthreads();

    int gidx = blockIdx.x * blockDim.x + threadIdx.x;
    int row = gidx >> 1;
    if (row >= B) return;
    const bool isOdd = (gidx & 1) != 0;
    const int jb = isOdd ? 10 : 0;   // this lane's neuron range (layers 1-3)
    const int kb = isOdd ? 4 : 0;    // this lane's output range (layer 4)

    float bb0 = X[row * 6 + 0], bb1 = X[row * 6 + 1], bb2 = X[row * 6 + 2];
    float bb3 = X[row * 6 + 3], bb4 = X[row * 6 + 4], bb5 = X[row * 6 + 5];

    // --- MLP, neuron-split across the lane pair ---
    float hA[10], hB[10];   // absolute h[0..9], h[10..19] (both lanes)
    {
        float acc[10];
        const f2* bv = (const f2*)&sb1[jb];
        #pragma unroll
        for (int p = 0; p < 5; p++) { f2 b = bv[p]; acc[2 * p] = b.x; acc[2 * p + 1] = b.y; }
        #pragma unroll
        for (int n = 0; n < 10; n++) {
            int j = jb + n;
            f4 w0 = *(const f4*)&tW1[j * 8];
            f2 w1 = *(const f2*)&tW1[j * 8 + 4];
            float a = acc[n];
            a = fmaf(bb0, w0.x, a); a = fmaf(bb1, w0.y, a); a = fmaf(bb2, w0.z, a);
            a = fmaf(bb3, w0.w, a); a = fmaf(bb4, w1.x, a); a = fmaf(bb5, w1.y, a);
            acc[n] = fast_tanh(a);
        }
        #pragma unroll
        for (int n = 0; n < 10; n++) {
            float t = dpp_swap(acc[n]);
            hA[n] = isOdd ? t : acc[n];
            hB[n] = isOdd ? acc[n] : t;
        }
    }
    #pragma unroll
    for (int layer = 0; layer < 2; layer++) {
        const float* tw = layer ? tW3 : tW2;
        const float* sb = layer ? sb3 : sb2;
        float acc[10];
        const f2* bv = (const f2*)&sb[jb];
        #pragma unroll
        for (int p = 0; p < 5; p++) { f2 b = bv[p]; acc[2 * p] = b.x; acc[2 * p + 1] = b.y; }
        #pragma unroll
        for (int n = 0; n < 10; n++) {
            int j = jb + n;
            const f4* w = (const f4*)&tw[j * 20];
            f4 w0 = w[0], w1 = w[1], w2 = w[2], w3 = w[3], w4 = w[4];
            float a = acc[n];
            a = fmaf(hA[0], w0.x, a); a = fmaf(hA[1], w0.y, a);
            a = fmaf(hA[2], w0.z, a); a = fmaf(hA[3], w0.w, a);
            a = fmaf(hA[4], w1.x, a); a = fmaf(hA[5], w1.y, a);
            a = fmaf(hA[6], w1.z, a); a = fmaf(hA[7], w1.w, a);
            a = fmaf(hA[8], w2.x, a); a = fmaf(hA[9], w2.y, a);
            a = fmaf(hB[0], w2.z, a); a = fmaf(hB[1], w2.w, a);
            a = fmaf(hB[2], w3.x, a); a = fmaf(hB[3], w3.y, a);
            a = fmaf(hB[4], w3.z, a); a = fmaf(hB[5], w3.w, a);
            a = fmaf(hB[6], w4.x, a); a = fmaf(hB[7], w4.y, a);
            a = fmaf(hB[8], w4.z, a); a = fmaf(hB[9], w4.w, a);
            acc[n] = fast_tanh(a);
        }
        #pragma unroll
        for (int n = 0; n < 10; n++) {
            float t = dpp_swap(acc[n]);
            hA[n] = isOdd ? t : acc[n];
            hB[n] = isOdd ? acc[n] : t;
        }
    }
    // L4: this lane's 4 outputs == exactly its z components (no exchange)
    float oz0, oz1, oz2, oz3;
    {
        f4 b = *(const f4*)&sb4[kb];
        float acc[4] = {b.x, b.y, b.z, b.w};
        #pragma unroll
        for (int n = 0; n < 4; n++) {
            int k = kb + n;
            const f4* w = (const f4*)&tW4[k * 20];
            f4 w0 = w[0], w1 = w[1], w2 = w[2], w3 = w[3], w4 = w[4];
            float a = acc[n];
            a = fmaf(hA[0], w0.x, a); a = fmaf(hA[1], w0.y, a);
            a = fmaf(hA[2], w0.z, a); a = fmaf(hA[3], w0.w, a);
            a = fmaf(hA[4], w1.x, a); a = fmaf(hA[5], w1.y, a);
            a = fmaf(hA[6], w1.z, a); a = fmaf(hA[7], w1.w, a);
            a = fmaf(hA[8], w2.x, a); a = fmaf(hA[9], w2.y, a);
            a = fmaf(hB[0], w2.z, a); a = fmaf(hB[1], w2.w, a);
            a = fmaf(hB[2], w3.x, a); a = fmaf(hB[3], w3.y, a);
            a = fmaf(hB[4], w3.z, a); a = fmaf(hB[5], w3.w, a);
            a = fmaf(hB[6], w4.x, a); a = fmaf(hB[7], w4.y, a);
            a = fmaf(hB[8], w4.z, a); a = fmaf(hB[9], w4.w, a);
            acc[n] = a;
        }
        oz0 = acc[0]; oz1 = acc[1]; oz2 = acc[2]; oz3 = acc[3];
    }

    // --- constants ---
    const float tau  = 0.18898223650461363f;   // 1/sqrt(28)
    const float c    = 0.03571428571428571f;   // tau*sigma = 1/28
    const float tauC = 1.8898223650461363f;    // tau * control_strength(10)

    float ot0 = tau - oz0, ot1 = tau - oz1, ot2 = tau - oz2, ot3 = tau - oz3;
    float oTI0 = ot0, oTI1 = ot1, oTI2 = ot2, oTI3 = ot3;

    float ox0 = fmaxf(oz0, 0.f), ox1 = fmaxf(oz1, 0.f);
    float ox2 = fmaxf(oz2, 0.f), ox3 = fmaxf(oz3, 0.f);
    float oxb0 = ox0, oxb1 = ox1, oxb2 = ox2, oxb3 = ox3;

    // dual-row constants: even rows (0,2,1) -> (cb0,cb2,cb1); odd (4,3,5)
    float cb0 = c * bb0, cb1 = c * bb1, cb2 = c * bb2;
    float cb3 = c * bb3, cb4 = c * bb4, cb5 = c * bb5;
    float cbq0 = isOdd ? cb4 : cb0;
    float cbq1 = isOdd ? cb3 : cb2;
    float cbq2 = isOdd ? cb5 : cb1;
    float Yq0 = 0.f, Yq1 = 0.f, Yq2 = 0.f;

    #pragma unroll 1
    for (int it = 0; it < N_ITERS; it++) {
        // xb exchange (4): rxb_i = partner's oxb_i
        float rxb0 = dpp_swap(oxb0), rxb1 = dpp_swap(oxb1);
        float rxb2 = dpp_swap(oxb2), rxb3 = dpp_swap(oxb3);

        // s-sums (12): even (s0,s2,s1), odd (s4,s3,s5)
        float op_a = oxb0 + rxb1;            // e: xb0+xb5 | o: xb4+xb1
        float op_b = oxb2 + rxb3;            // e: xb2+xb7 | o: garbage
        float op_c = oxb3 + rxb2;            // e: garbage | o: xb7+xb2
        float op_d = isOdd ? op_c : op_b;
        float sq0  = op_a + op_d;            // e: s0 | o: s4
        float op_e = oxb1 + rxb2;            // e: xb1+xb6 | o: xb5+xb2
        float op_f = isOdd ? rxb3 : oxb0;    // e: xb0 | o: xb3
        float sq1  = op_e + op_f;            // e: s2 | o: s3
        float op_g = oxb1 + oxb3;            // e: xb1+xb3
        float op_h = oxb0 + oxb2;            //            o: xb4+xb6
        float op_i = isOdd ? op_h : op_g;
        float sq2  = op_i + rxb0;            // e: s1 | o: s5

        // Y updates (9): Y = max(0, fma(c,s,Y) - cb)
        Yq0 = fmaxf(0.f, fmaf(c, sq0, Yq0) - cbq0);
        Yq1 = fmaxf(0.f, fmaf(c, sq1, Yq1) - cbq1);
        Yq2 = fmaxf(0.f, fmaf(c, sq2, Yq2) - cbq2);

        // Y exchange (3): e gets (Y4,Y3,Y5); o gets (Y0,Y2,Y1)
        float rY0 = dpp_swap(Yq0), rY1 = dpp_swap(Yq1), rY2 = dpp_swap(Yq2);

        // column sums (11): even cols 0-3, odd cols 4-7
        float op_j = Yq0 + rY2;              // e: Y0+Y5 | o: Y4+Y1
        float op_k = isOdd ? Yq2 : Yq1;      // e: Y2    | o: Y5
        float colq0 = op_j + op_k;           // e: col0  | o: col4
        float op_l = Yq1 + rY0;              // e: Y2+Y4 | o: Y3+Y0
        float op_p = isOdd ? 0.f : Yq2;      // e: Y1    | o: 0
        float colq1 = op_l + op_p;           // e: col1  | o: col5
        float op_m = Yq0 + rY0;              // e: Y0+Y4 | o: Y4+Y0 (=col7)
        float op_n = rY1 + Yq2;              // e: Y3+Y1 (=col3) | o: Y2+Y5 (=col6)
        float op_o = op_m + rY1;             // e: Y0+Y4+Y3 (=col2) | o: garbage
        float colq2 = isOdd ? op_n : op_o;   // e: col2 | o: col6
        float colq3 = isOdd ? op_m : op_n;   // e: col3 | o: col7

        // TI (8): TI = max(t, fma(-c, xb, TI))
        oTI0 = fmaxf(ot0, fmaf(-c, oxb0, oTI0));
        oTI1 = fmaxf(ot1, fmaf(-c, oxb1, oTI1));
        oTI2 = fmaxf(ot2, fmaf(-c, oxb2, oTI2));
        oTI3 = fmaxf(ot3, fmaf(-c, oxb3, oTI3));

        // d = (x + TI) - col  (8)
        float od0 = (ox0 + oTI0) - colq0;
        float od1 = (ox1 + oTI1) - colq1;
        float od2 = (ox2 + oTI2) - colq2;
        float od3 = (ox3 + oTI3) - colq3;

        // nsq (6): local 4-term + cross-lane add (commutative => identical)
        float nl = od0 * od0;
        nl = fmaf(od1, od1, nl);
        nl = fmaf(od2, od2, nl);
        nl = fmaf(od3, od3, nl);
        float rn = dpp_swap(nl);
        float nsq = nl + rn;

        // scale (3): max(0, 1 - tauC*rsq(nsq)); rsq(0)=inf -> 0 == ref clamp
        float rs = __builtin_amdgcn_rsqf(nsq);
        float scale = fmaxf(0.f, fmaf(-tauC, rs, 1.f));

        // xn + xb commit (8)
        float xn0 = fmaf(scale, od0, oz0);
        float xn1 = fmaf(scale, od1, oz1);
        float xn2 = fmaf(scale, od2, oz2);
        float xn3 = fmaf(scale, od3, oz3);
        oxb0 = fmaf(2.f, xn0, -ox0); ox0 = xn0;
        oxb1 = fmaf(2.f, xn1, -ox1); ox1 = xn1;
        oxb2 = fmaf(2.f, xn2, -ox2); ox2 = xn2;
        oxb3 = fmaf(2.f, xn3, -ox3); ox3 = xn3;
    }

    // even lane: comps 0-3 at out4[row*2]; odd: comps 4-7 at out4[row*2+1]
    float4* out4 = (float4*)out;
    out4[gidx] = make_float4(ox0, ox1, ox2, ox3);
}

extern "C" void kernel_launch(void* const* d_in, const int* in_sizes, int n_in,
                              void* d_out, int out_size, void* d_ws, size_t ws_size,
                              hipStream_t stream) {
    const float* X  = (const float*)d_in[0];
    const float* W1 = (const float*)d_in[1];
    const float* b1 = (const float*)d_in[2];
    const float* W2 = (const float*)d_in[3];
    const float* b2 = (const float*)d_in[4];
    const float* W3 = (const float*)d_in[5];
    const float* b3 = (const float*)d_in[6];
    const float* W4 = (const float*)d_in[7];
    const float* b4 = (const float*)d_in[8];
    float* out = (float*)d_out;

    int B = in_sizes[0] / 6;
    const int block = 64;
    long long threads = (long long)B * 2;
    int grid = (int)((threads + block - 1) / block);
    hipLaunchKernelGGL(matchnet_kernel, dim3(grid), dim3(block), 0, stream,
                       X, W1, b1, W2, b2, W3, b3, W4, b4, out, B);
}